// Round 2
// baseline (169.081 us; speedup 1.0000x reference)
//
#include <hip/hip_runtime.h>
#include <hip/hip_bf16.h>
#include <stdint.h>

#define PHh 16
#define PWw 16
#define Bn  32
#define Cn  3
#define Hn  512
#define Wn  512
#define Nn  196
#define Dn  768
#define Kn  768            // C*PH*PW
#define Mn  (Bn * Nn)      // 6272

typedef __attribute__((ext_vector_type(8))) short   short8;
typedef __attribute__((ext_vector_type(4))) float   f32x4;

// ---------------------------------------------------------------------------
// Kernel 1: gather patches from x, convert to bf16, write A[M][K] (K-major)
// ---------------------------------------------------------------------------
__global__ void gather_patches(const float* __restrict__ x,
                               const int* __restrict__ centers,
                               __hip_bfloat16* __restrict__ A) {
    int idx = blockIdx.x * blockDim.x + threadIdx.x;   // 4 elements per thread
    const int total4 = Mn * Kn / 4;
    if (idx >= total4) return;
    int e = idx * 4;
    int m = e / Kn;                 // patch row (b*N + n)
    int k = e - m * Kn;             // multiple of 4
    int b = m / Nn;
    int ch = centers[m * 2 + 0];
    int cw = centers[m * 2 + 1];
    int sh = min(max(ch - PHh / 2, 0), Hn - PHh);
    int sw = min(max(cw - PWw / 2, 0), Wn - PWw);
    int c  = k >> 8;                // k / 256
    int r  = k & 255;
    int ph = r >> 4;
    int pw = r & 15;                // multiple of 4
    const float* src = x + ((size_t)(b * Cn + c) * Hn + (sh + ph)) * Wn + (sw + pw);
    __hip_bfloat16 v[4];
    v[0] = __float2bfloat16(src[0]);
    v[1] = __float2bfloat16(src[1]);
    v[2] = __float2bfloat16(src[2]);
    v[3] = __float2bfloat16(src[3]);
    *reinterpret_cast<ushort4*>(A + e) = *reinterpret_cast<const ushort4*>(v);
}

// ---------------------------------------------------------------------------
// Kernel 2: Wt[d][k] = bf16(W[k][d])  (LDS-tiled transpose, 32x32 tiles)
// ---------------------------------------------------------------------------
__global__ void transpose_w(const float* __restrict__ W,
                            __hip_bfloat16* __restrict__ Wt) {
    __shared__ float tile[32][33];
    int d0 = blockIdx.x * 32;
    int k0 = blockIdx.y * 32;
    int lx = threadIdx.x & 31;
    int ly = threadIdx.x >> 5;     // 0..7
#pragma unroll
    for (int i = 0; i < 4; ++i) {
        int kk = ly + i * 8;
        tile[kk][lx] = W[(size_t)(k0 + kk) * Dn + d0 + lx];
    }
    __syncthreads();
#pragma unroll
    for (int i = 0; i < 4; ++i) {
        int dd = ly + i * 8;
        Wt[(size_t)(d0 + dd) * Kn + k0 + lx] = __float2bfloat16(tile[lx][dd]);
    }
}

// ---------------------------------------------------------------------------
// Kernel 3: C[M][D] = A[M][K] @ Wt[D][K]^T + bias   (bf16 MFMA, fp32 out)
// 128x128 tile, 4 waves (2x2), BK=32, global_load_lds width-16 staging.
// ---------------------------------------------------------------------------
__device__ __forceinline__ void gload_lds16(const __hip_bfloat16* g,
                                            __hip_bfloat16* l) {
    __builtin_amdgcn_global_load_lds(
        (const __attribute__((address_space(1))) void*)g,
        (__attribute__((address_space(3))) void*)l, 16, 0, 0);
}

__global__ __launch_bounds__(256, 2) void gemm_bt(
    const __hip_bfloat16* __restrict__ A,
    const __hip_bfloat16* __restrict__ Bt,
    const float* __restrict__ bias,
    float* __restrict__ C) {
    __shared__ __hip_bfloat16 As[128 * 32];
    __shared__ __hip_bfloat16 Bs[128 * 32];

    const int bm = blockIdx.x;       // 0..48  (rows of C)
    const int bn = blockIdx.y;       // 0..5   (cols of C)
    const int tid = threadIdx.x;
    const int w = tid >> 6;          // wave 0..3
    const int l = tid & 63;
    const int wr = w >> 1;           // wave row 0..1  (64 rows each)
    const int wc = w & 1;            // wave col 0..1  (64 cols each)

    // staging source addressing: lane covers 16B = 8 bf16 of one row
    const int srow = w * 16 + (l >> 2);      // 0..63 (call0), +64 (call1)
    const int skk  = (l & 3) * 8;
    const __hip_bfloat16* Ag = A  + (size_t)(bm * 128 + srow) * Kn + skk;
    const __hip_bfloat16* Bg = Bt + (size_t)(bn * 128 + srow) * Kn + skk;

    // fragment addressing
    const int fr = l & 15;           // row (A) / col (B) within 16
    const int fq = l >> 4;           // k-chunk 0..3

    f32x4 acc[4][4] = {};

    for (int t = 0; t < Kn / 32; ++t) {
        gload_lds16(Ag,           As + w * 512);          // rows 0..63
        gload_lds16(Ag + 64 * Kn, As + 2048 + w * 512);   // rows 64..127
        gload_lds16(Bg,           Bs + w * 512);
        gload_lds16(Bg + 64 * Kn, Bs + 2048 + w * 512);
        Ag += 32; Bg += 32;
        __syncthreads();              // drains vmcnt+lgkmcnt

        short8 af[4], bfrag[4];
#pragma unroll
        for (int m = 0; m < 4; ++m)
            af[m] = *reinterpret_cast<const short8*>(
                &As[(wr * 64 + m * 16 + fr) * 32 + fq * 8]);
#pragma unroll
        for (int n = 0; n < 4; ++n)
            bfrag[n] = *reinterpret_cast<const short8*>(
                &Bs[(wc * 64 + n * 16 + fr) * 32 + fq * 8]);
#pragma unroll
        for (int m = 0; m < 4; ++m)
#pragma unroll
            for (int n = 0; n < 4; ++n)
                acc[m][n] = __builtin_amdgcn_mfma_f32_16x16x32_bf16(
                    af[m], bfrag[n], acc[m][n], 0, 0, 0);
        __syncthreads();
    }

    // epilogue: C/D layout col=lane&15, row=(lane>>4)*4+j
#pragma unroll
    for (int n = 0; n < 4; ++n) {
        int col = bn * 128 + wc * 64 + n * 16 + fr;
        float bv = bias[col];
#pragma unroll
        for (int m = 0; m < 4; ++m) {
            int row0 = bm * 128 + wr * 64 + m * 16 + fq * 4;
#pragma unroll
            for (int j = 0; j < 4; ++j)
                C[(size_t)(row0 + j) * Dn + col] = acc[m][n][j] + bv;
        }
    }
}

// ---------------------------------------------------------------------------
// Fallback (ws too small): naive fp32, one thread per output element
// ---------------------------------------------------------------------------
__global__ void naive_patch_embed(const float* __restrict__ x,
                                  const int* __restrict__ centers,
                                  const float* __restrict__ W,
                                  const float* __restrict__ bias,
                                  float* __restrict__ out) {
    int idx = blockIdx.x * blockDim.x + threadIdx.x;
    if (idx >= Mn * Dn) return;
    int m = idx / Dn;
    int d = idx - m * Dn;
    int b = m / Nn;
    int ch = centers[m * 2 + 0];
    int cw = centers[m * 2 + 1];
    int sh = min(max(ch - 8, 0), Hn - PHh);
    int sw = min(max(cw - 8, 0), Wn - PWw);
    float accv = bias[d];
    for (int c = 0; c < Cn; ++c)
        for (int ph = 0; ph < PHh; ++ph) {
            const float* row = x + ((size_t)(b * Cn + c) * Hn + sh + ph) * Wn + sw;
            const float* wr = W + (size_t)(c * 256 + ph * 16) * Dn + d;
#pragma unroll
            for (int pw = 0; pw < PWw; ++pw)
                accv += row[pw] * wr[(size_t)pw * Dn];
        }
    out[idx] = accv;
}

// ---------------------------------------------------------------------------
extern "C" void kernel_launch(void* const* d_in, const int* in_sizes, int n_in,
                              void* d_out, int out_size, void* d_ws, size_t ws_size,
                              hipStream_t stream) {
    const float* x       = (const float*)d_in[0];
    const int*   centers = (const int*)d_in[1];
    const float* W       = (const float*)d_in[2];
    const float* bias    = (const float*)d_in[3];
    float*       out     = (float*)d_out;

    const size_t needA = (size_t)Mn * Kn * sizeof(__hip_bfloat16);  // 9,633,792
    const size_t needW = (size_t)Kn * Dn * sizeof(__hip_bfloat16);  // 1,179,648

    if (ws_size >= needA + needW) {
        __hip_bfloat16* Abf = (__hip_bfloat16*)d_ws;
        __hip_bfloat16* Wt  = (__hip_bfloat16*)((char*)d_ws + needA);

        int g1 = (Mn * Kn / 4 + 255) / 256;
        gather_patches<<<g1, 256, 0, stream>>>(x, centers, Abf);

        dim3 g2(Dn / 32, Kn / 32);
        transpose_w<<<g2, 256, 0, stream>>>(W, Wt);

        dim3 g3(Mn / 128, Dn / 128);
        gemm_bt<<<g3, 256, 0, stream>>>(Abf, Wt, bias, out);
    } else {
        int g = (Mn * Dn + 255) / 256;
        naive_patch_embed<<<g, 256, 0, stream>>>(x, centers, W, bias, out);
    }
}

// Round 4
// 166.031 us; speedup vs baseline: 1.0184x; 1.0184x over previous
//
#include <hip/hip_runtime.h>
#include <hip/hip_bf16.h>
#include <stdint.h>

#define PHh 16
#define PWw 16
#define Bn  32
#define Cn  3
#define Hn  512
#define Wn  512
#define Nn  196
#define Dn  768
#define Kn  768            // C*PH*PW
#define Mn  (Bn * Nn)      // 6272

typedef __attribute__((ext_vector_type(8))) short   short8;
typedef __attribute__((ext_vector_type(4))) float   f32x4;

// ---------------------------------------------------------------------------
// Kernel 1: gather patches from x, convert to bf16, write A[M][K] (K-major)
// 8 elements per thread: two independent float4 loads (ILP), one 16B store.
// ---------------------------------------------------------------------------
__global__ void gather_patches(const float* __restrict__ x,
                               const int* __restrict__ centers,
                               __hip_bfloat16* __restrict__ A) {
    int idx = blockIdx.x * blockDim.x + threadIdx.x;   // 8 elements per thread
    const int total8 = Mn * Kn / 8;
    if (idx >= total8) return;
    int e = idx * 8;
    int m = e / Kn;                 // patch row (b*N + n)
    int k = e - m * Kn;             // multiple of 8
    int b = m / Nn;
    int ch = centers[m * 2 + 0];
    int cw = centers[m * 2 + 1];
    int sh = min(max(ch - PHh / 2, 0), Hn - PHh);
    int sw = min(max(cw - PWw / 2, 0), Wn - PWw);
    int c  = k >> 8;                // k / 256
    int r  = k & 255;
    int ph = r >> 4;
    int pw = r & 15;                // 0 or 8
    const float* src = x + ((size_t)(b * Cn + c) * Hn + (sh + ph)) * Wn + (sw + pw);
    float4 lo = *reinterpret_cast<const float4*>(src);
    float4 hi = *reinterpret_cast<const float4*>(src + 4);
    __hip_bfloat16 v[8];
    v[0] = __float2bfloat16(lo.x); v[1] = __float2bfloat16(lo.y);
    v[2] = __float2bfloat16(lo.z); v[3] = __float2bfloat16(lo.w);
    v[4] = __float2bfloat16(hi.x); v[5] = __float2bfloat16(hi.y);
    v[6] = __float2bfloat16(hi.z); v[7] = __float2bfloat16(hi.w);
    *reinterpret_cast<short8*>(A + e) = *reinterpret_cast<const short8*>(v);
}

// ---------------------------------------------------------------------------
// Kernel 2: Wt[d][k] = bf16(W[k][d])  (LDS-tiled transpose, 32x32 tiles)
// ---------------------------------------------------------------------------
__global__ void transpose_w(const float* __restrict__ W,
                            __hip_bfloat16* __restrict__ Wt) {
    __shared__ float tile[32][33];
    int d0 = blockIdx.x * 32;
    int k0 = blockIdx.y * 32;
    int lx = threadIdx.x & 31;
    int ly = threadIdx.x >> 5;     // 0..7
#pragma unroll
    for (int i = 0; i < 4; ++i) {
        int kk = ly + i * 8;
        tile[kk][lx] = W[(size_t)(k0 + kk) * Dn + d0 + lx];
    }
    __syncthreads();
#pragma unroll
    for (int i = 0; i < 4; ++i) {
        int dd = ly + i * 8;
        Wt[(size_t)(d0 + dd) * Kn + k0 + lx] = __float2bfloat16(tile[lx][dd]);
    }
}

// ---------------------------------------------------------------------------
// Kernel 3: C[M][D] = A[M][K] @ Wt[D][K]^T + bias   (bf16 MFMA, fp32 out)
// 64x128 tile (BM=64, BN=128) -> grid 98x6 = 588 blocks (~2.3/CU) so barrier
// drains overlap across co-resident blocks. 4 waves (2x2), BK=32,
// global_load_lds width-16 staging into linear LDS.
// ---------------------------------------------------------------------------
__device__ __forceinline__ void gload_lds16(const __hip_bfloat16* g,
                                            __hip_bfloat16* l) {
    __builtin_amdgcn_global_load_lds(
        (const __attribute__((address_space(1))) void*)g,
        (__attribute__((address_space(3))) void*)l, 16, 0, 0);
}

__global__ __launch_bounds__(256, 4) void gemm_bt(
    const __hip_bfloat16* __restrict__ A,
    const __hip_bfloat16* __restrict__ Bt,
    const float* __restrict__ bias,
    float* __restrict__ C) {
    __shared__ __hip_bfloat16 As[64 * 32];    // 4 KiB
    __shared__ __hip_bfloat16 Bs[128 * 32];   // 8 KiB

    const int bm = blockIdx.x;       // 0..97  (row tiles of 64)
    const int bn = blockIdx.y;       // 0..5   (col tiles of 128)
    const int tid = threadIdx.x;
    const int w = tid >> 6;          // wave 0..3
    const int l = tid & 63;
    const int wr = w >> 1;           // wave row 0..1  (32 rows each)
    const int wc = w & 1;            // wave col 0..1  (64 cols each)

    // staging source addressing: lane covers 16B = 8 bf16 of one row
    const int srow = w * 16 + (l >> 2);      // 0..63
    const int skk  = (l & 3) * 8;
    const __hip_bfloat16* Ag = A  + (size_t)(bm * 64  + srow) * Kn + skk;
    const __hip_bfloat16* Bg = Bt + (size_t)(bn * 128 + srow) * Kn + skk;

    // fragment addressing
    const int fr = l & 15;           // row (A) / col (B) within 16
    const int fq = l >> 4;           // k-chunk 0..3

    f32x4 acc[2][4] = {};

    for (int t = 0; t < Kn / 32; ++t) {
        gload_lds16(Ag,           As + w * 512);          // A rows 0..63
        gload_lds16(Bg,           Bs + w * 512);          // B rows 0..63
        gload_lds16(Bg + 64 * Kn, Bs + 2048 + w * 512);   // B rows 64..127
        Ag += 32; Bg += 32;
        __syncthreads();              // drains vmcnt+lgkmcnt

        short8 af[2], bfrag[4];
#pragma unroll
        for (int m = 0; m < 2; ++m)
            af[m] = *reinterpret_cast<const short8*>(
                &As[(wr * 32 + m * 16 + fr) * 32 + fq * 8]);
#pragma unroll
        for (int n = 0; n < 4; ++n)
            bfrag[n] = *reinterpret_cast<const short8*>(
                &Bs[(wc * 64 + n * 16 + fr) * 32 + fq * 8]);
#pragma unroll
        for (int m = 0; m < 2; ++m)
#pragma unroll
            for (int n = 0; n < 4; ++n)
                acc[m][n] = __builtin_amdgcn_mfma_f32_16x16x32_bf16(
                    af[m], bfrag[n], acc[m][n], 0, 0, 0);
        __syncthreads();
    }

    // epilogue: C/D layout col=lane&15, row=(lane>>4)*4+j
#pragma unroll
    for (int n = 0; n < 4; ++n) {
        int col = bn * 128 + wc * 64 + n * 16 + fr;
        float bv = bias[col];
#pragma unroll
        for (int m = 0; m < 2; ++m) {
            int row0 = bm * 64 + wr * 32 + m * 16 + fq * 4;
#pragma unroll
            for (int j = 0; j < 4; ++j)
                C[(size_t)(row0 + j) * Dn + col] = acc[m][n][j] + bv;
        }
    }
}

// ---------------------------------------------------------------------------
// Fallback (ws too small): naive fp32, one thread per output element
// ---------------------------------------------------------------------------
__global__ void naive_patch_embed(const float* __restrict__ x,
                                  const int* __restrict__ centers,
                                  const float* __restrict__ W,
                                  const float* __restrict__ bias,
                                  float* __restrict__ out) {
    int idx = blockIdx.x * blockDim.x + threadIdx.x;
    if (idx >= Mn * Dn) return;
    int m = idx / Dn;
    int d = idx - m * Dn;
    int b = m / Nn;
    int ch = centers[m * 2 + 0];
    int cw = centers[m * 2 + 1];
    int sh = min(max(ch - 8, 0), Hn - PHh);
    int sw = min(max(cw - 8, 0), Wn - PWw);
    float accv = bias[d];
    for (int c = 0; c < Cn; ++c)
        for (int ph = 0; ph < PHh; ++ph) {
            const float* row = x + ((size_t)(b * Cn + c) * Hn + sh + ph) * Wn + sw;
            const float* wr = W + (size_t)(c * 256 + ph * 16) * Dn + d;
#pragma unroll
            for (int pw = 0; pw < PWw; ++pw)
                accv += row[pw] * wr[(size_t)pw * Dn];
        }
    out[idx] = accv;
}

// ---------------------------------------------------------------------------
extern "C" void kernel_launch(void* const* d_in, const int* in_sizes, int n_in,
                              void* d_out, int out_size, void* d_ws, size_t ws_size,
                              hipStream_t stream) {
    const float* x       = (const float*)d_in[0];
    const int*   centers = (const int*)d_in[1];
    const float* W       = (const float*)d_in[2];
    const float* bias    = (const float*)d_in[3];
    float*       out     = (float*)d_out;

    const size_t needA = (size_t)Mn * Kn * sizeof(__hip_bfloat16);  // 9,633,792
    const size_t needW = (size_t)Kn * Dn * sizeof(__hip_bfloat16);  // 1,179,648

    if (ws_size >= needA + needW) {
        __hip_bfloat16* Abf = (__hip_bfloat16*)d_ws;
        __hip_bfloat16* Wt  = (__hip_bfloat16*)((char*)d_ws + needA);

        int g1 = (Mn * Kn / 8 + 255) / 256;   // 2352 blocks
        gather_patches<<<g1, 256, 0, stream>>>(x, centers, Abf);

        dim3 g2(Dn / 32, Kn / 32);
        transpose_w<<<g2, 256, 0, stream>>>(W, Wt);

        dim3 g3(Mn / 64, Dn / 128);           // 98 x 6 = 588 blocks
        gemm_bt<<<g3, 256, 0, stream>>>(Abf, Wt, bias, out);
    } else {
        int g = (Mn * Dn + 255) / 256;
        naive_patch_embed<<<g, 256, 0, stream>>>(x, centers, W, bias, out);
    }
}

// Round 5
// 165.727 us; speedup vs baseline: 1.0202x; 1.0018x over previous
//
#include <hip/hip_runtime.h>
#include <hip/hip_bf16.h>
#include <stdint.h>

#define PHh 16
#define PWw 16
#define Bn  32
#define Cn  3
#define Hn  512
#define Wn  512
#define Nn  196
#define Dn  768
#define Kn  768            // C*PH*PW
#define Mn  (Bn * Nn)      // 6272

typedef __attribute__((ext_vector_type(8))) short   short8;
typedef __attribute__((ext_vector_type(4))) float   f32x4;

// ---------------------------------------------------------------------------
// Kernel 1: Wt[d][k] = bf16(W[k][d])  (LDS-tiled transpose, 32x32 tiles)
// ---------------------------------------------------------------------------
__global__ void transpose_w(const float* __restrict__ W,
                            __hip_bfloat16* __restrict__ Wt) {
    __shared__ float tile[32][33];
    int d0 = blockIdx.x * 32;
    int k0 = blockIdx.y * 32;
    int lx = threadIdx.x & 31;
    int ly = threadIdx.x >> 5;     // 0..7
#pragma unroll
    for (int i = 0; i < 4; ++i) {
        int kk = ly + i * 8;
        tile[kk][lx] = W[(size_t)(k0 + kk) * Dn + d0 + lx];
    }
    __syncthreads();
#pragma unroll
    for (int i = 0; i < 4; ++i) {
        int dd = ly + i * 8;
        Wt[(size_t)(d0 + dd) * Kn + k0 + lx] = __float2bfloat16(tile[lx][dd]);
    }
}

// ---------------------------------------------------------------------------
// Kernel 2 (fused): gather patches from x -> bf16 LDS A-tile, B via
// global_load_lds from Wt, MFMA, bias, store. BM=64, BN=128, BK=32.
// Grid 98x6 = 588 blocks, 4 waves (2x2), LB(256,4) -> 4 blocks/CU.
// A-staging is reg-staged (scattered source + fp32->bf16 convert), with
// T14 issue-early: step t+1's pixel loads are issued before the barrier so
// HBM/L3 latency hides under the MFMA phase.
// ---------------------------------------------------------------------------
__device__ __forceinline__ void gload_lds16(const __hip_bfloat16* g,
                                            __hip_bfloat16* l) {
    __builtin_amdgcn_global_load_lds(
        (const __attribute__((address_space(1))) void*)g,
        (__attribute__((address_space(3))) void*)l, 16, 0, 0);
}

__global__ __launch_bounds__(256, 4) void fused_patch_gemm(
    const float* __restrict__ x,
    const int* __restrict__ centers,
    const __hip_bfloat16* __restrict__ Bt,
    const float* __restrict__ bias,
    float* __restrict__ C) {
    __shared__ __hip_bfloat16 As[64 * 32];    // 4 KiB
    __shared__ __hip_bfloat16 Bs[128 * 32];   // 8 KiB

    const int bm = blockIdx.x;       // 0..97  (row tiles of 64)
    const int bn = blockIdx.y;       // 0..5   (col tiles of 128)
    const int tid = threadIdx.x;
    const int w = tid >> 6;          // wave 0..3
    const int l = tid & 63;
    const int wr = w >> 1;           // wave row 0..1  (32 rows each)
    const int wc = w & 1;            // wave col 0..1  (64 cols each)

    // ---- A-gather role: thread = (row ml, quarter q); 8 px per thread/step
    const int ml = tid >> 2;         // 0..63 : patch row within tile
    const int q  = tid & 3;          // 0..3  : 8-elem quarter of the 32-k step
    const int m  = bm * 64 + ml;     // global patch index
    const int b  = m / Nn;
    const int2 cc = *reinterpret_cast<const int2*>(centers + 2 * m);
    const int sh = min(max(cc.x - PHh / 2, 0), Hn - PHh);
    const int sw = min(max(cc.y - PWw / 2, 0), Wn - PWw);
    const float* xbase = x + ((size_t)(b * Cn) * Hn + sh) * Wn + sw;
    // LDS dest: ml*32 + q*8 == tid*8  -> linear 16B/thread, conflict-free
    __hip_bfloat16* adst = As + tid * 8;

    // ---- B staging (global_load_lds, linear LDS): lane covers 16B of a row
    const int srow = w * 16 + (l >> 2);      // 0..63
    const int skk  = (l & 3) * 8;
    const __hip_bfloat16* Bg = Bt + (size_t)(bn * 128 + srow) * Kn + skk;

    // ---- fragment addressing
    const int fr = l & 15;           // row (A) / col (B) within 16
    const int fq = l >> 4;           // k-chunk 0..3

    f32x4 acc[2][4] = {};

    // pixel source for K-step t (k0 = t*32 + q*8):
    //   c = k0>>8, ph = (k0>>4)&15, pw = k0&15 (0 or 8)
    auto srcAt = [&](int t) -> const float* {
        int k0 = t * 32 + q * 8;
        int c  = k0 >> 8;
        int ph = (k0 >> 4) & 15;
        int pw = k0 & 15;
        return xbase + ((size_t)c * Hn + ph) * Wn + pw;
    };

    // prologue: preload pixels for t=0
    const float* s0 = srcAt(0);
    float4 lo = *reinterpret_cast<const float4*>(s0);
    float4 hi = *reinterpret_cast<const float4*>(s0 + 4);

    for (int t = 0; t < Kn / 32; ++t) {
        // issue B staging for this step (stays in flight until barrier)
        gload_lds16(Bg,           Bs + w * 512);          // B rows 0..63
        gload_lds16(Bg + 64 * Kn, Bs + 2048 + w * 512);   // B rows 64..127
        Bg += 32;

        // convert current pixels -> bf16, write A subtile (ds_write_b128)
        __hip_bfloat16 v[8];
        v[0] = __float2bfloat16(lo.x); v[1] = __float2bfloat16(lo.y);
        v[2] = __float2bfloat16(lo.z); v[3] = __float2bfloat16(lo.w);
        v[4] = __float2bfloat16(hi.x); v[5] = __float2bfloat16(hi.y);
        v[6] = __float2bfloat16(hi.z); v[7] = __float2bfloat16(hi.w);
        *reinterpret_cast<short8*>(adst) = *reinterpret_cast<const short8*>(v);

        // T14 issue-early: next step's pixel loads fly during MFMA phase
        const float* sn = srcAt(t < Kn / 32 - 1 ? t + 1 : 0);
        float4 nlo = *reinterpret_cast<const float4*>(sn);
        float4 nhi = *reinterpret_cast<const float4*>(sn + 4);

        __syncthreads();              // drains A ds_write + B gload

        short8 af[2], bfrag[4];
#pragma unroll
        for (int mm = 0; mm < 2; ++mm)
            af[mm] = *reinterpret_cast<const short8*>(
                &As[(wr * 32 + mm * 16 + fr) * 32 + fq * 8]);
#pragma unroll
        for (int n = 0; n < 4; ++n)
            bfrag[n] = *reinterpret_cast<const short8*>(
                &Bs[(wc * 64 + n * 16 + fr) * 32 + fq * 8]);
#pragma unroll
        for (int mm = 0; mm < 2; ++mm)
#pragma unroll
            for (int n = 0; n < 4; ++n)
                acc[mm][n] = __builtin_amdgcn_mfma_f32_16x16x32_bf16(
                    af[mm], bfrag[n], acc[mm][n], 0, 0, 0);
        __syncthreads();

        lo = nlo; hi = nhi;
    }

    // epilogue: C/D layout col=lane&15, row=(lane>>4)*4+j
#pragma unroll
    for (int n = 0; n < 4; ++n) {
        int col = bn * 128 + wc * 64 + n * 16 + fr;
        float bv = bias[col];
#pragma unroll
        for (int mm = 0; mm < 2; ++mm) {
            int row0 = bm * 64 + wr * 32 + mm * 16 + fq * 4;
#pragma unroll
            for (int j = 0; j < 4; ++j)
                C[(size_t)(row0 + j) * Dn + col] = acc[mm][n][j] + bv;
        }
    }
}

// ---------------------------------------------------------------------------
// Fallback (ws too small): naive fp32, one thread per output element
// ---------------------------------------------------------------------------
__global__ void naive_patch_embed(const float* __restrict__ x,
                                  const int* __restrict__ centers,
                                  const float* __restrict__ W,
                                  const float* __restrict__ bias,
                                  float* __restrict__ out) {
    int idx = blockIdx.x * blockDim.x + threadIdx.x;
    if (idx >= Mn * Dn) return;
    int m = idx / Dn;
    int d = idx - m * Dn;
    int b = m / Nn;
    int ch = centers[m * 2 + 0];
    int cw = centers[m * 2 + 1];
    int sh = min(max(ch - 8, 0), Hn - PHh);
    int sw = min(max(cw - 8, 0), Wn - PWw);
    float accv = bias[d];
    for (int c = 0; c < Cn; ++c)
        for (int ph = 0; ph < PHh; ++ph) {
            const float* row = x + ((size_t)(b * Cn + c) * Hn + sh + ph) * Wn + sw;
            const float* wr = W + (size_t)(c * 256 + ph * 16) * Dn + d;
#pragma unroll
            for (int pw = 0; pw < PWw; ++pw)
                accv += row[pw] * wr[(size_t)pw * Dn];
        }
    out[idx] = accv;
}

// ---------------------------------------------------------------------------
extern "C" void kernel_launch(void* const* d_in, const int* in_sizes, int n_in,
                              void* d_out, int out_size, void* d_ws, size_t ws_size,
                              hipStream_t stream) {
    const float* x       = (const float*)d_in[0];
    const int*   centers = (const int*)d_in[1];
    const float* W       = (const float*)d_in[2];
    const float* bias    = (const float*)d_in[3];
    float*       out     = (float*)d_out;

    const size_t needW = (size_t)Kn * Dn * sizeof(__hip_bfloat16);  // 1,179,648

    if (ws_size >= needW) {
        __hip_bfloat16* Wt = (__hip_bfloat16*)d_ws;

        dim3 g2(Dn / 32, Kn / 32);
        transpose_w<<<g2, 256, 0, stream>>>(W, Wt);

        dim3 g3(Mn / 64, Dn / 128);           // 98 x 6 = 588 blocks
        fused_patch_gemm<<<g3, 256, 0, stream>>>(x, centers, Wt, bias, out);
    } else {
        int g = (Mn * Dn + 255) / 256;
        naive_patch_embed<<<g, 256, 0, stream>>>(x, centers, W, bias, out);
    }
}